// Round 1
// baseline (1346.253 us; speedup 1.0000x reference)
//
#include <hip/hip_runtime.h>
#include <hip/hip_bf16.h>
#include <cstddef>

// GCN: h0 = relu(spmm(x@W0^T)); h1 = relu(spmm(h0@W1^T)); out = spmm(h1@W2^T)
// spmm(h)[r] = sum_{e: rows[e]==r} vals[e] * h[cols[e]]
// Strategy: build CSR on-device each launch (hist -> scan -> scatter),
// fp32 register-blocked GEMM (no fp32 MFMA on CDNA4), wave-per-row SpMM.

#define THREADS_PB 256

__global__ __launch_bounds__(256) void zero_i32(int* p, int n) {
    int i = blockIdx.x * 256 + threadIdx.x;
    if (i < n) p[i] = 0;
}

__global__ __launch_bounds__(256) void hist_kernel(const int* __restrict__ rows,
                                                   int* __restrict__ counts, int ne) {
    int e = blockIdx.x * 256 + threadIdx.x;
    if (e < ne) atomicAdd(&counts[rows[e]], 1);
}

__global__ __launch_bounds__(256) void block_totals(const int* __restrict__ counts,
                                                    int* __restrict__ bsums, int n) {
    __shared__ int s[256];
    int t = threadIdx.x;
    int i = blockIdx.x * 256 + t;
    s[t] = (i < n) ? counts[i] : 0;
    __syncthreads();
    for (int off = 128; off > 0; off >>= 1) {
        if (t < off) s[t] += s[t + off];
        __syncthreads();
    }
    if (t == 0) bsums[blockIdx.x] = s[0];
}

// single block, 512 threads: exclusive scan of nb (<512) block sums in place
__global__ __launch_bounds__(512) void scan_sums(int* bsums, int nb) {
    __shared__ int s[512];
    int t = threadIdx.x;
    int v = (t < nb) ? bsums[t] : 0;
    s[t] = v;
    __syncthreads();
    for (int off = 1; off < 512; off *= 2) {
        int u = (t >= off) ? s[t - off] : 0;
        __syncthreads();
        s[t] += u;
        __syncthreads();
    }
    if (t < nb) bsums[t] = s[t] - v;  // exclusive
}

__global__ __launch_bounds__(256) void scan_final(const int* __restrict__ counts,
                                                  const int* __restrict__ bsums,
                                                  int* __restrict__ row_ptr,
                                                  int* __restrict__ cur, int n) {
    __shared__ int s[256];
    int t = threadIdx.x;
    int i = blockIdx.x * 256 + t;
    int v = (i < n) ? counts[i] : 0;
    s[t] = v;
    __syncthreads();
    for (int off = 1; off < 256; off *= 2) {
        int u = (t >= off) ? s[t - off] : 0;
        __syncthreads();
        s[t] += u;
        __syncthreads();
    }
    int excl = s[t] - v + bsums[blockIdx.x];
    if (i < n) {
        row_ptr[i] = excl;
        cur[i] = excl;
        if (i == n - 1) row_ptr[n] = excl + v;
    }
}

__global__ __launch_bounds__(256) void scatter_k(const int* __restrict__ rows,
                                                 const int* __restrict__ cols,
                                                 const float* __restrict__ vals,
                                                 int* __restrict__ cur,
                                                 int* __restrict__ col_s,
                                                 float* __restrict__ val_s, int ne) {
    int e = blockIdx.x * 256 + threadIdx.x;
    if (e >= ne) return;
    int r = rows[e];
    int p = atomicAdd(&cur[r], 1);
    col_s[p] = cols[e];
    val_s[p] = vals[e];
}

// C[M,N] = A[M,K] * W[N,K]^T  (fp32, register-blocked)
template <int K, int N, int BM, int BN, int BK, int TM, int TN>
__global__ __launch_bounds__(256) void gemm_nt(const float* __restrict__ A,
                                               const float* __restrict__ W,
                                               float* __restrict__ C, int M) {
    constexpr int THREADS = (BM / TM) * (BN / TN);
    static_assert(THREADS == 256, "thread count");
    __shared__ float As[BK][BM + 4];
    __shared__ float Bs[BK][BN + 4];
    const int tid = threadIdx.x;
    const int tx = tid % (BN / TN);
    const int ty = tid / (BN / TN);
    const int rowBase = blockIdx.x * BM;

    float acc[TM][TN];
#pragma unroll
    for (int i = 0; i < TM; i++)
#pragma unroll
        for (int j = 0; j < TN; j++) acc[i][j] = 0.f;

    for (int k0 = 0; k0 < K; k0 += BK) {
        // stage A tile (BM x BK) transposed into As[k][m]
        constexpr int A_F4 = BM * BK / 4;
        constexpr int A_PER = A_F4 / THREADS;
#pragma unroll
        for (int i = 0; i < A_PER; i++) {
            int f4 = tid + i * THREADS;
            int r = f4 / (BK / 4);
            int cq = f4 % (BK / 4);
            float4 v = make_float4(0.f, 0.f, 0.f, 0.f);
            int grow = rowBase + r;
            if (grow < M) v = *(const float4*)(A + (size_t)grow * K + k0 + cq * 4);
            As[cq * 4 + 0][r] = v.x;
            As[cq * 4 + 1][r] = v.y;
            As[cq * 4 + 2][r] = v.z;
            As[cq * 4 + 3][r] = v.w;
        }
        // stage W tile (BN x BK) transposed into Bs[k][n]
        constexpr int B_F4 = BN * BK / 4;
        constexpr int B_PER = B_F4 / THREADS;
#pragma unroll
        for (int i = 0; i < B_PER; i++) {
            int f4 = tid + i * THREADS;
            int nr = f4 / (BK / 4);
            int cq = f4 % (BK / 4);
            float4 v = *(const float4*)(W + (size_t)nr * K + k0 + cq * 4);
            Bs[cq * 4 + 0][nr] = v.x;
            Bs[cq * 4 + 1][nr] = v.y;
            Bs[cq * 4 + 2][nr] = v.z;
            Bs[cq * 4 + 3][nr] = v.w;
        }
        __syncthreads();
#pragma unroll
        for (int kk = 0; kk < BK; kk++) {
            float a[TM], b[TN];
#pragma unroll
            for (int i = 0; i < TM; i++) a[i] = As[kk][ty * TM + i];
#pragma unroll
            for (int j = 0; j < TN; j++) b[j] = Bs[kk][tx * TN + j];
#pragma unroll
            for (int i = 0; i < TM; i++)
#pragma unroll
                for (int j = 0; j < TN; j++) acc[i][j] += a[i] * b[j];
        }
        __syncthreads();
    }
#pragma unroll
    for (int i = 0; i < TM; i++) {
        int grow = rowBase + ty * TM + i;
        if (grow < M) {
#pragma unroll
            for (int j = 0; j < TN; j += 4) {
                float4 v = make_float4(acc[i][j], acc[i][j + 1], acc[i][j + 2], acc[i][j + 3]);
                *(float4*)(C + (size_t)grow * N + tx * TN + j) = v;
            }
        }
    }
}

// one wave per row: out[r,:] = (relu?) sum_e val_s[e] * G[col_s[e], :]
template <int N, bool RELU>
__global__ __launch_bounds__(256) void spmm_csr(const int* __restrict__ row_ptr,
                                                const int* __restrict__ col_s,
                                                const float* __restrict__ val_s,
                                                const float* __restrict__ G,
                                                float* __restrict__ H, int n) {
    int row = blockIdx.x * 4 + (threadIdx.x >> 6);
    int lane = threadIdx.x & 63;
    if (row >= n) return;
    int s = row_ptr[row];
    int e = row_ptr[row + 1];
    constexpr int J = N / 64;
    float acc[J];
#pragma unroll
    for (int j = 0; j < J; j++) acc[j] = 0.f;
    for (int p = s; p < e; p++) {
        int c = col_s[p];
        float v = val_s[p];
        const float* g = G + (size_t)c * N;
#pragma unroll
        for (int j = 0; j < J; j++) acc[j] += v * g[lane + j * 64];
    }
#pragma unroll
    for (int j = 0; j < J; j++) {
        float o = acc[j];
        if (RELU) o = fmaxf(o, 0.f);
        H[(size_t)row * N + lane + j * 64] = o;
    }
}

static inline size_t align_up(size_t x, size_t a) { return (x + a - 1) & ~(a - 1); }

extern "C" void kernel_launch(void* const* d_in, const int* in_sizes, int n_in,
                              void* d_out, int out_size, void* d_ws, size_t ws_size,
                              hipStream_t stream) {
    const float* x = (const float*)d_in[0];
    const int* rows = (const int*)d_in[1];
    const int* cols = (const int*)d_in[2];
    const float* vals = (const float*)d_in[3];
    const float* W0 = (const float*)d_in[4];
    const float* W1 = (const float*)d_in[5];
    const float* W2 = (const float*)d_in[6];
    float* out = (float*)d_out;

    const int IN = 512, HID = 128;
    const int n = in_sizes[0] / IN;   // 100000
    const int ne = in_sizes[1];       // 1600000

    // workspace carve-up
    char* ws = (char*)d_ws;
    size_t off = 0;
    float* g = (float*)(ws + off); off = align_up(off + (size_t)n * HID * 4, 512);
    float* h = (float*)(ws + off); off = align_up(off + (size_t)n * HID * 4, 512);
    int* col_s = (int*)(ws + off); off = align_up(off + (size_t)ne * 4, 512);
    float* val_s = (float*)(ws + off); off = align_up(off + (size_t)ne * 4, 512);
    int* counts = (int*)(ws + off); off = align_up(off + (size_t)n * 4, 512);
    int* row_ptr = (int*)(ws + off); off = align_up(off + (size_t)(n + 1) * 4, 512);
    int* cur = (int*)(ws + off); off = align_up(off + (size_t)n * 4, 512);
    int* bsums = (int*)(ws + off); off = align_up(off + 512 * 4, 512);

    const int nb = (n + 255) / 256;       // 391 (< 512)
    const int eb = (ne + 255) / 256;

    // ---- build CSR ----
    zero_i32<<<nb, 256, 0, stream>>>(counts, n);
    hist_kernel<<<eb, 256, 0, stream>>>(rows, counts, ne);
    block_totals<<<nb, 256, 0, stream>>>(counts, bsums, n);
    scan_sums<<<1, 512, 0, stream>>>(bsums, nb);
    scan_final<<<nb, 256, 0, stream>>>(counts, bsums, row_ptr, cur, n);
    scatter_k<<<eb, 256, 0, stream>>>(rows, cols, vals, cur, col_s, val_s, ne);

    const int gblocks = (n + 127) / 128;
    const int sblocks = (n + 3) / 4;

    // ---- layer 0: g = x @ W0^T ; h = relu(spmm(g)) ----
    gemm_nt<512, 128, 128, 128, 32, 8, 8><<<gblocks, 256, 0, stream>>>(x, W0, g, n);
    spmm_csr<128, true><<<sblocks, 256, 0, stream>>>(row_ptr, col_s, val_s, g, h, n);

    // ---- layer 1: g = h @ W1^T ; h = relu(spmm(g)) ----
    gemm_nt<128, 128, 128, 128, 32, 8, 8><<<gblocks, 256, 0, stream>>>(h, W1, g, n);
    spmm_csr<128, true><<<sblocks, 256, 0, stream>>>(row_ptr, col_s, val_s, g, h, n);

    // ---- layer 2: g = h @ W2^T ; out = spmm(g) ----
    gemm_nt<128, 64, 128, 64, 32, 8, 4><<<gblocks, 256, 0, stream>>>(h, W2, g, n);
    spmm_csr<64, false><<<sblocks, 256, 0, stream>>>(row_ptr, col_s, val_s, g, out, n);
}

// Round 2
// 1025.953 us; speedup vs baseline: 1.3122x; 1.3122x over previous
//
#include <hip/hip_runtime.h>
#include <hip/hip_bf16.h>
#include <cstddef>

// GCN: h0 = relu(spmm(x@W0^T)); h1 = relu(spmm(h0@W1^T)); out = spmm(h1@W2^T)
// R2: GEMMs moved to bf16 MFMA (16x16x32), weights pre-converted to bf16,
// activations converted fp32->bf16 during LDS staging. SpMM/CSR unchanged.

typedef unsigned short ushort_t;
using frag_t = __attribute__((ext_vector_type(8))) short;   // 8 bf16
using accf4 = __attribute__((ext_vector_type(4))) float;    // 4 fp32

__device__ __forceinline__ ushort_t f2bf(float f) {
    unsigned int u = __float_as_uint(f);
    u += 0x7FFF + ((u >> 16) & 1);   // RNE
    return (ushort_t)(u >> 16);
}

// ---------------- CSR build ----------------

__global__ __launch_bounds__(256) void zero_i32(int* p, int n) {
    int i = blockIdx.x * 256 + threadIdx.x;
    if (i < n) p[i] = 0;
}

__global__ __launch_bounds__(256) void hist_kernel(const int* __restrict__ rows,
                                                   int* __restrict__ counts, int ne) {
    int e = blockIdx.x * 256 + threadIdx.x;
    if (e < ne) atomicAdd(&counts[rows[e]], 1);
}

__global__ __launch_bounds__(256) void block_totals(const int* __restrict__ counts,
                                                    int* __restrict__ bsums, int n) {
    __shared__ int s[256];
    int t = threadIdx.x;
    int i = blockIdx.x * 256 + t;
    s[t] = (i < n) ? counts[i] : 0;
    __syncthreads();
    for (int off = 128; off > 0; off >>= 1) {
        if (t < off) s[t] += s[t + off];
        __syncthreads();
    }
    if (t == 0) bsums[blockIdx.x] = s[0];
}

__global__ __launch_bounds__(512) void scan_sums(int* bsums, int nb) {
    __shared__ int s[512];
    int t = threadIdx.x;
    int v = (t < nb) ? bsums[t] : 0;
    s[t] = v;
    __syncthreads();
    for (int off = 1; off < 512; off *= 2) {
        int u = (t >= off) ? s[t - off] : 0;
        __syncthreads();
        s[t] += u;
        __syncthreads();
    }
    if (t < nb) bsums[t] = s[t] - v;  // exclusive
}

__global__ __launch_bounds__(256) void scan_final(const int* __restrict__ counts,
                                                  const int* __restrict__ bsums,
                                                  int* __restrict__ row_ptr,
                                                  int* __restrict__ cur, int n) {
    __shared__ int s[256];
    int t = threadIdx.x;
    int i = blockIdx.x * 256 + t;
    int v = (i < n) ? counts[i] : 0;
    s[t] = v;
    __syncthreads();
    for (int off = 1; off < 256; off *= 2) {
        int u = (t >= off) ? s[t - off] : 0;
        __syncthreads();
        s[t] += u;
        __syncthreads();
    }
    int excl = s[t] - v + bsums[blockIdx.x];
    if (i < n) {
        row_ptr[i] = excl;
        cur[i] = excl;
        if (i == n - 1) row_ptr[n] = excl + v;
    }
}

__global__ __launch_bounds__(256) void scatter_k(const int* __restrict__ rows,
                                                 const int* __restrict__ cols,
                                                 const float* __restrict__ vals,
                                                 int* __restrict__ cur,
                                                 int* __restrict__ col_s,
                                                 float* __restrict__ val_s, int ne) {
    int e = blockIdx.x * 256 + threadIdx.x;
    if (e >= ne) return;
    int r = rows[e];
    int p = atomicAdd(&cur[r], 1);
    col_s[p] = cols[e];
    val_s[p] = vals[e];
}

// ---------------- weight convert ----------------

__global__ __launch_bounds__(256) void f32_to_bf16_k(const float* __restrict__ a,
                                                     ushort_t* __restrict__ b, int n) {
    int i = blockIdx.x * 256 + threadIdx.x;
    if (i < n) b[i] = f2bf(a[i]);
}

// ---------------- bf16 MFMA GEMM: C[M,N] = A[M,K] * W[N,K]^T ----------------
// A fp32 (converted during staging), W pre-converted bf16 [N,K] row-major.
// Block = 256 threads = 4 waves in 2x2; wave tile = (BM/2) x (BN/2);
// 16x16x32 MFMA. LDS rows padded +8 bf16 (16 B) -> 2-way bank alias (free),
// keeps 16 B alignment for ds_read_b128.

template <int K, int N, int BM, int BN, int BK>
__global__ __launch_bounds__(256) void gemm_bf16(const float* __restrict__ A,
                                                 const ushort_t* __restrict__ Wb,
                                                 float* __restrict__ C, int M) {
    constexpr int WM = BM / 2;        // 64
    constexpr int WN = BN / 2;        // 64 or 32
    constexpr int TI = WM / 16;       // 4
    constexpr int TJ = WN / 16;       // 4 or 2
    constexpr int LDA = BK + 8;

    __shared__ __align__(16) ushort_t As[BM][LDA];
    __shared__ __align__(16) ushort_t Bs[BN][LDA];

    const int tid = threadIdx.x;
    const int lane = tid & 63;
    const int wid = tid >> 6;
    const int wm = wid >> 1;          // 0..1
    const int wn = wid & 1;           // 0..1
    const int rowBase = blockIdx.x * BM;

    const int lrow = lane & 15;       // m (or n) within 16
    const int kq = lane >> 4;         // 0..3

    accf4 acc[TI][TJ];
#pragma unroll
    for (int i = 0; i < TI; i++)
#pragma unroll
        for (int j = 0; j < TJ; j++) acc[i][j] = accf4{0.f, 0.f, 0.f, 0.f};

    for (int k0 = 0; k0 < K; k0 += BK) {
        // ---- stage A: BM x BK fp32 -> bf16 ----
        constexpr int A_PER = BM * BK / 4 / 256;   // float4 per thread
#pragma unroll
        for (int i = 0; i < A_PER; i++) {
            int idx = tid + i * 256;
            int r = idx / (BK / 4);
            int c4 = idx % (BK / 4);
            int grow = rowBase + r;
            float4 v = make_float4(0.f, 0.f, 0.f, 0.f);
            if (grow < M) v = *(const float4*)(A + (size_t)grow * K + k0 + c4 * 4);
            ushort_t p[4] = {f2bf(v.x), f2bf(v.y), f2bf(v.z), f2bf(v.w)};
            *(uint2*)&As[r][c4 * 4] = *(uint2*)p;
        }
        // ---- stage B: BN x BK bf16 direct ----
        constexpr int B_PER = BN * BK / 8 / 256;   // uint4 (8 bf16) per thread
#pragma unroll
        for (int i = 0; i < B_PER; i++) {
            int idx = tid + i * 256;
            int r = idx / (BK / 8);
            int c8 = idx % (BK / 8);
            uint4 v = *(const uint4*)(Wb + (size_t)r * K + k0 + c8 * 8);
            *(uint4*)&Bs[r][c8 * 8] = v;
        }
        __syncthreads();

#pragma unroll
        for (int ks = 0; ks < BK / 32; ks++) {
            const int kb = ks * 32 + kq * 8;
            frag_t a[TI], b[TJ];
#pragma unroll
            for (int i = 0; i < TI; i++)
                a[i] = *(const frag_t*)&As[wm * WM + i * 16 + lrow][kb];
#pragma unroll
            for (int j = 0; j < TJ; j++)
                b[j] = *(const frag_t*)&Bs[wn * WN + j * 16 + lrow][kb];
#pragma unroll
            for (int i = 0; i < TI; i++)
#pragma unroll
                for (int j = 0; j < TJ; j++)
                    acc[i][j] = __builtin_amdgcn_mfma_f32_16x16x32_bf16(
                        a[i], b[j], acc[i][j], 0, 0, 0);
        }
        __syncthreads();
    }

    // ---- epilogue: C/D layout col=lane&15, row=(lane>>4)*4+reg ----
#pragma unroll
    for (int i = 0; i < TI; i++) {
#pragma unroll
        for (int j = 0; j < TJ; j++) {
            int col = wn * WN + j * 16 + lrow;
#pragma unroll
            for (int r = 0; r < 4; r++) {
                int grow = rowBase + wm * WM + i * 16 + kq * 4 + r;
                if (grow < M) C[(size_t)grow * N + col] = acc[i][j][r];
            }
        }
    }
}

// ---------------- SpMM (CSR, wave per row) ----------------

template <int N, bool RELU>
__global__ __launch_bounds__(256) void spmm_csr(const int* __restrict__ row_ptr,
                                                const int* __restrict__ col_s,
                                                const float* __restrict__ val_s,
                                                const float* __restrict__ G,
                                                float* __restrict__ H, int n) {
    int row = blockIdx.x * 4 + (threadIdx.x >> 6);
    int lane = threadIdx.x & 63;
    if (row >= n) return;
    int s = row_ptr[row];
    int e = row_ptr[row + 1];
    constexpr int J = N / 64;
    float acc[J];
#pragma unroll
    for (int j = 0; j < J; j++) acc[j] = 0.f;
    for (int p = s; p < e; p++) {
        int c = col_s[p];
        float v = val_s[p];
        const float* g = G + (size_t)c * N;
#pragma unroll
        for (int j = 0; j < J; j++) acc[j] += v * g[lane + j * 64];
    }
#pragma unroll
    for (int j = 0; j < J; j++) {
        float o = acc[j];
        if (RELU) o = fmaxf(o, 0.f);
        H[(size_t)row * N + lane + j * 64] = o;
    }
}

static inline size_t align_up(size_t x, size_t a) { return (x + a - 1) & ~(a - 1); }

extern "C" void kernel_launch(void* const* d_in, const int* in_sizes, int n_in,
                              void* d_out, int out_size, void* d_ws, size_t ws_size,
                              hipStream_t stream) {
    const float* x = (const float*)d_in[0];
    const int* rows = (const int*)d_in[1];
    const int* cols = (const int*)d_in[2];
    const float* vals = (const float*)d_in[3];
    const float* W0 = (const float*)d_in[4];
    const float* W1 = (const float*)d_in[5];
    const float* W2 = (const float*)d_in[6];
    float* out = (float*)d_out;

    const int IN = 512, HID = 128, OUT = 64;
    const int n = in_sizes[0] / IN;   // 100000
    const int ne = in_sizes[1];       // 1600000

    // workspace carve-up
    char* ws = (char*)d_ws;
    size_t off = 0;
    float* g = (float*)(ws + off); off = align_up(off + (size_t)n * HID * 4, 512);
    float* h = (float*)(ws + off); off = align_up(off + (size_t)n * HID * 4, 512);
    int* col_s = (int*)(ws + off); off = align_up(off + (size_t)ne * 4, 512);
    float* val_s = (float*)(ws + off); off = align_up(off + (size_t)ne * 4, 512);
    int* counts = (int*)(ws + off); off = align_up(off + (size_t)n * 4, 512);
    int* row_ptr = (int*)(ws + off); off = align_up(off + (size_t)(n + 1) * 4, 512);
    int* cur = (int*)(ws + off); off = align_up(off + (size_t)n * 4, 512);
    int* bsums = (int*)(ws + off); off = align_up(off + 512 * 4, 512);
    ushort_t* Wb0 = (ushort_t*)(ws + off); off = align_up(off + (size_t)HID * IN * 2, 512);
    ushort_t* Wb1 = (ushort_t*)(ws + off); off = align_up(off + (size_t)HID * HID * 2, 512);
    ushort_t* Wb2 = (ushort_t*)(ws + off); off = align_up(off + (size_t)OUT * HID * 2, 512);

    const int nb = (n + 255) / 256;
    const int eb = (ne + 255) / 256;

    // ---- build CSR ----
    zero_i32<<<nb, 256, 0, stream>>>(counts, n);
    hist_kernel<<<eb, 256, 0, stream>>>(rows, counts, ne);
    block_totals<<<nb, 256, 0, stream>>>(counts, bsums, n);
    scan_sums<<<1, 512, 0, stream>>>(bsums, nb);
    scan_final<<<nb, 256, 0, stream>>>(counts, bsums, row_ptr, cur, n);
    scatter_k<<<eb, 256, 0, stream>>>(rows, cols, vals, cur, col_s, val_s, ne);

    // ---- weights -> bf16 ----
    f32_to_bf16_k<<<(HID * IN + 255) / 256, 256, 0, stream>>>(W0, Wb0, HID * IN);
    f32_to_bf16_k<<<(HID * HID + 255) / 256, 256, 0, stream>>>(W1, Wb1, HID * HID);
    f32_to_bf16_k<<<(OUT * HID + 255) / 256, 256, 0, stream>>>(W2, Wb2, OUT * HID);

    const int gblocks = (n + 127) / 128;
    const int sblocks = (n + 3) / 4;

    // ---- layer 0 ----
    gemm_bf16<512, 128, 128, 128, 64><<<gblocks, 256, 0, stream>>>(x, Wb0, g, n);
    spmm_csr<128, true><<<sblocks, 256, 0, stream>>>(row_ptr, col_s, val_s, g, h, n);

    // ---- layer 1 ----
    gemm_bf16<128, 128, 128, 128, 64><<<gblocks, 256, 0, stream>>>(h, Wb1, g, n);
    spmm_csr<128, true><<<sblocks, 256, 0, stream>>>(row_ptr, col_s, val_s, g, h, n);

    // ---- layer 2 ----
    gemm_bf16<128, 64, 128, 64, 64><<<gblocks, 256, 0, stream>>>(h, Wb2, g, n);
    spmm_csr<64, false><<<sblocks, 256, 0, stream>>>(row_ptr, col_s, val_s, g, out, n);
}

// Round 3
// 834.992 us; speedup vs baseline: 1.6123x; 1.2287x over previous
//
#include <hip/hip_runtime.h>
#include <hip/hip_bf16.h>
#include <cstddef>

// GCN: h0 = relu(spmm(x@W0^T)); h1 = relu(spmm(h0@W1^T)); out = spmm(h1@W2^T)
// R3: all activation intermediates (g, h) stored as bf16. SpMM gathers bf16,
// accumulates fp32. GEMMs read bf16 A directly for layers 1/2.

typedef unsigned short ushort_t;
using frag_t = __attribute__((ext_vector_type(8))) short;   // 8 bf16
using accf4 = __attribute__((ext_vector_type(4))) float;    // 4 fp32

__device__ __forceinline__ ushort_t f2bf(float f) {
    unsigned int u = __float_as_uint(f);
    u += 0x7FFF + ((u >> 16) & 1);   // RNE
    return (ushort_t)(u >> 16);
}
__device__ __forceinline__ float bf2f(ushort_t u) {
    return __uint_as_float((unsigned int)u << 16);
}

// ---------------- CSR build ----------------

__global__ __launch_bounds__(256) void zero_i32(int* p, int n) {
    int i = blockIdx.x * 256 + threadIdx.x;
    if (i < n) p[i] = 0;
}

__global__ __launch_bounds__(256) void hist_kernel(const int* __restrict__ rows,
                                                   int* __restrict__ counts, int ne) {
    int e = blockIdx.x * 256 + threadIdx.x;
    if (e < ne) atomicAdd(&counts[rows[e]], 1);
}

__global__ __launch_bounds__(256) void block_totals(const int* __restrict__ counts,
                                                    int* __restrict__ bsums, int n) {
    __shared__ int s[256];
    int t = threadIdx.x;
    int i = blockIdx.x * 256 + t;
    s[t] = (i < n) ? counts[i] : 0;
    __syncthreads();
    for (int off = 128; off > 0; off >>= 1) {
        if (t < off) s[t] += s[t + off];
        __syncthreads();
    }
    if (t == 0) bsums[blockIdx.x] = s[0];
}

__global__ __launch_bounds__(512) void scan_sums(int* bsums, int nb) {
    __shared__ int s[512];
    int t = threadIdx.x;
    int v = (t < nb) ? bsums[t] : 0;
    s[t] = v;
    __syncthreads();
    for (int off = 1; off < 512; off *= 2) {
        int u = (t >= off) ? s[t - off] : 0;
        __syncthreads();
        s[t] += u;
        __syncthreads();
    }
    if (t < nb) bsums[t] = s[t] - v;  // exclusive
}

__global__ __launch_bounds__(256) void scan_final(const int* __restrict__ counts,
                                                  const int* __restrict__ bsums,
                                                  int* __restrict__ row_ptr,
                                                  int* __restrict__ cur, int n) {
    __shared__ int s[256];
    int t = threadIdx.x;
    int i = blockIdx.x * 256 + t;
    int v = (i < n) ? counts[i] : 0;
    s[t] = v;
    __syncthreads();
    for (int off = 1; off < 256; off *= 2) {
        int u = (t >= off) ? s[t - off] : 0;
        __syncthreads();
        s[t] += u;
        __syncthreads();
    }
    int excl = s[t] - v + bsums[blockIdx.x];
    if (i < n) {
        row_ptr[i] = excl;
        cur[i] = excl;
        if (i == n - 1) row_ptr[n] = excl + v;
    }
}

__global__ __launch_bounds__(256) void scatter_k(const int* __restrict__ rows,
                                                 const int* __restrict__ cols,
                                                 const float* __restrict__ vals,
                                                 int* __restrict__ cur,
                                                 int* __restrict__ col_s,
                                                 float* __restrict__ val_s, int ne) {
    int e = blockIdx.x * 256 + threadIdx.x;
    if (e >= ne) return;
    int r = rows[e];
    int p = atomicAdd(&cur[r], 1);
    col_s[p] = cols[e];
    val_s[p] = vals[e];
}

// ---------------- weight convert ----------------

__global__ __launch_bounds__(256) void f32_to_bf16_k(const float* __restrict__ a,
                                                     ushort_t* __restrict__ b, int n) {
    int i = blockIdx.x * 256 + threadIdx.x;
    if (i < n) b[i] = f2bf(a[i]);
}

// ---------------- bf16 MFMA GEMM: C[M,N] = A[M,K] * W[N,K]^T ----------------
// ABF16: A already bf16 [M,K]; else fp32 converted during staging.
// Output C written as bf16.

template <int K, int N, int BM, int BN, int BK, bool ABF16>
__global__ __launch_bounds__(256) void gemm_bf16(const void* __restrict__ Av,
                                                 const ushort_t* __restrict__ Wb,
                                                 ushort_t* __restrict__ C, int M) {
    constexpr int WM = BM / 2;        // 64
    constexpr int WN = BN / 2;        // 64 or 32
    constexpr int TI = WM / 16;       // 4
    constexpr int TJ = WN / 16;       // 4 or 2
    constexpr int LDA = BK + 8;

    __shared__ __align__(16) ushort_t As[BM][LDA];
    __shared__ __align__(16) ushort_t Bs[BN][LDA];

    const int tid = threadIdx.x;
    const int lane = tid & 63;
    const int wid = tid >> 6;
    const int wm = wid >> 1;
    const int wn = wid & 1;
    const int rowBase = blockIdx.x * BM;

    const int lrow = lane & 15;
    const int kq = lane >> 4;

    accf4 acc[TI][TJ];
#pragma unroll
    for (int i = 0; i < TI; i++)
#pragma unroll
        for (int j = 0; j < TJ; j++) acc[i][j] = accf4{0.f, 0.f, 0.f, 0.f};

    for (int k0 = 0; k0 < K; k0 += BK) {
        if (ABF16) {
            const ushort_t* A = (const ushort_t*)Av;
            constexpr int A_PER = BM * BK / 8 / 256;
#pragma unroll
            for (int i = 0; i < A_PER; i++) {
                int idx = tid + i * 256;
                int r = idx / (BK / 8);
                int c8 = idx % (BK / 8);
                int grow = rowBase + r;
                uint4 v = make_uint4(0, 0, 0, 0);
                if (grow < M) v = *(const uint4*)(A + (size_t)grow * K + k0 + c8 * 8);
                *(uint4*)&As[r][c8 * 8] = v;
            }
        } else {
            const float* A = (const float*)Av;
            constexpr int A_PER = BM * BK / 4 / 256;
#pragma unroll
            for (int i = 0; i < A_PER; i++) {
                int idx = tid + i * 256;
                int r = idx / (BK / 4);
                int c4 = idx % (BK / 4);
                int grow = rowBase + r;
                float4 v = make_float4(0.f, 0.f, 0.f, 0.f);
                if (grow < M) v = *(const float4*)(A + (size_t)grow * K + k0 + c4 * 4);
                ushort_t p[4] = {f2bf(v.x), f2bf(v.y), f2bf(v.z), f2bf(v.w)};
                *(uint2*)&As[r][c4 * 4] = *(uint2*)p;
            }
        }
        constexpr int B_PER = BN * BK / 8 / 256;
#pragma unroll
        for (int i = 0; i < B_PER; i++) {
            int idx = tid + i * 256;
            int r = idx / (BK / 8);
            int c8 = idx % (BK / 8);
            uint4 v = *(const uint4*)(Wb + (size_t)r * K + k0 + c8 * 8);
            *(uint4*)&Bs[r][c8 * 8] = v;
        }
        __syncthreads();

#pragma unroll
        for (int ks = 0; ks < BK / 32; ks++) {
            const int kb = ks * 32 + kq * 8;
            frag_t a[TI], b[TJ];
#pragma unroll
            for (int i = 0; i < TI; i++)
                a[i] = *(const frag_t*)&As[wm * WM + i * 16 + lrow][kb];
#pragma unroll
            for (int j = 0; j < TJ; j++)
                b[j] = *(const frag_t*)&Bs[wn * WN + j * 16 + lrow][kb];
#pragma unroll
            for (int i = 0; i < TI; i++)
#pragma unroll
                for (int j = 0; j < TJ; j++)
                    acc[i][j] = __builtin_amdgcn_mfma_f32_16x16x32_bf16(
                        a[i], b[j], acc[i][j], 0, 0, 0);
        }
        __syncthreads();
    }

    // epilogue: C/D layout col=lane&15, row=(lane>>4)*4+reg; write bf16
#pragma unroll
    for (int i = 0; i < TI; i++) {
#pragma unroll
        for (int j = 0; j < TJ; j++) {
            int col = wn * WN + j * 16 + lrow;
#pragma unroll
            for (int r = 0; r < 4; r++) {
                int grow = rowBase + wm * WM + i * 16 + kq * 4 + r;
                if (grow < M) C[(size_t)grow * N + col] = f2bf(acc[i][j][r]);
            }
        }
    }
}

// ---------------- SpMM (CSR, wave per row, bf16 gather) ----------------

// N=128: each lane loads one uint (2 bf16) per edge.
template <bool RELU>
__global__ __launch_bounds__(256) void spmm_csr_128(const int* __restrict__ row_ptr,
                                                    const int* __restrict__ col_s,
                                                    const float* __restrict__ val_s,
                                                    const ushort_t* __restrict__ G,
                                                    ushort_t* __restrict__ H, int n) {
    int row = blockIdx.x * 4 + (threadIdx.x >> 6);
    int lane = threadIdx.x & 63;
    if (row >= n) return;
    int s = row_ptr[row];
    int e = row_ptr[row + 1];
    float a0 = 0.f, a1 = 0.f;
    int p = s;
    for (; p + 1 < e; p += 2) {
        int c0 = col_s[p], c1 = col_s[p + 1];
        float v0 = val_s[p], v1 = val_s[p + 1];
        unsigned int u0 = *(const unsigned int*)(G + (size_t)c0 * 128 + lane * 2);
        unsigned int u1 = *(const unsigned int*)(G + (size_t)c1 * 128 + lane * 2);
        a0 += v0 * bf2f((ushort_t)(u0 & 0xffff));
        a1 += v0 * bf2f((ushort_t)(u0 >> 16));
        a0 += v1 * bf2f((ushort_t)(u1 & 0xffff));
        a1 += v1 * bf2f((ushort_t)(u1 >> 16));
    }
    if (p < e) {
        int c0 = col_s[p];
        float v0 = val_s[p];
        unsigned int u0 = *(const unsigned int*)(G + (size_t)c0 * 128 + lane * 2);
        a0 += v0 * bf2f((ushort_t)(u0 & 0xffff));
        a1 += v0 * bf2f((ushort_t)(u0 >> 16));
    }
    if (RELU) { a0 = fmaxf(a0, 0.f); a1 = fmaxf(a1, 0.f); }
    unsigned int packed = (unsigned int)f2bf(a0) | ((unsigned int)f2bf(a1) << 16);
    *(unsigned int*)(H + (size_t)row * 128 + lane * 2) = packed;
}

// N=64, fp32 output (final layer): each lane loads one ushort per edge.
__global__ __launch_bounds__(256) void spmm_csr_64f(const int* __restrict__ row_ptr,
                                                    const int* __restrict__ col_s,
                                                    const float* __restrict__ val_s,
                                                    const ushort_t* __restrict__ G,
                                                    float* __restrict__ H, int n) {
    int row = blockIdx.x * 4 + (threadIdx.x >> 6);
    int lane = threadIdx.x & 63;
    if (row >= n) return;
    int s = row_ptr[row];
    int e = row_ptr[row + 1];
    float a0 = 0.f;
    int p = s;
    for (; p + 1 < e; p += 2) {
        int c0 = col_s[p], c1 = col_s[p + 1];
        float v0 = val_s[p], v1 = val_s[p + 1];
        float g0 = bf2f(G[(size_t)c0 * 64 + lane]);
        float g1 = bf2f(G[(size_t)c1 * 64 + lane]);
        a0 += v0 * g0 + v1 * g1;
    }
    if (p < e) {
        a0 += val_s[p] * bf2f(G[(size_t)col_s[p] * 64 + lane]);
    }
    H[(size_t)row * 64 + lane] = a0;
}

static inline size_t align_up(size_t x, size_t a) { return (x + a - 1) & ~(a - 1); }

extern "C" void kernel_launch(void* const* d_in, const int* in_sizes, int n_in,
                              void* d_out, int out_size, void* d_ws, size_t ws_size,
                              hipStream_t stream) {
    const float* x = (const float*)d_in[0];
    const int* rows = (const int*)d_in[1];
    const int* cols = (const int*)d_in[2];
    const float* vals = (const float*)d_in[3];
    const float* W0 = (const float*)d_in[4];
    const float* W1 = (const float*)d_in[5];
    const float* W2 = (const float*)d_in[6];
    float* out = (float*)d_out;

    const int IN = 512, HID = 128, OUT = 64;
    const int n = in_sizes[0] / IN;   // 100000
    const int ne = in_sizes[1];       // 1600000

    // workspace carve-up
    char* ws = (char*)d_ws;
    size_t off = 0;
    ushort_t* g = (ushort_t*)(ws + off); off = align_up(off + (size_t)n * HID * 2, 512);
    ushort_t* h = (ushort_t*)(ws + off); off = align_up(off + (size_t)n * HID * 2, 512);
    int* col_s = (int*)(ws + off); off = align_up(off + (size_t)ne * 4, 512);
    float* val_s = (float*)(ws + off); off = align_up(off + (size_t)ne * 4, 512);
    int* counts = (int*)(ws + off); off = align_up(off + (size_t)n * 4, 512);
    int* row_ptr = (int*)(ws + off); off = align_up(off + (size_t)(n + 1) * 4, 512);
    int* cur = (int*)(ws + off); off = align_up(off + (size_t)n * 4, 512);
    int* bsums = (int*)(ws + off); off = align_up(off + 512 * 4, 512);
    ushort_t* Wb0 = (ushort_t*)(ws + off); off = align_up(off + (size_t)HID * IN * 2, 512);
    ushort_t* Wb1 = (ushort_t*)(ws + off); off = align_up(off + (size_t)HID * HID * 2, 512);
    ushort_t* Wb2 = (ushort_t*)(ws + off); off = align_up(off + (size_t)OUT * HID * 2, 512);

    const int nb = (n + 255) / 256;
    const int eb = (ne + 255) / 256;

    // ---- build CSR ----
    zero_i32<<<nb, 256, 0, stream>>>(counts, n);
    hist_kernel<<<eb, 256, 0, stream>>>(rows, counts, ne);
    block_totals<<<nb, 256, 0, stream>>>(counts, bsums, n);
    scan_sums<<<1, 512, 0, stream>>>(bsums, nb);
    scan_final<<<nb, 256, 0, stream>>>(counts, bsums, row_ptr, cur, n);
    scatter_k<<<eb, 256, 0, stream>>>(rows, cols, vals, cur, col_s, val_s, ne);

    // ---- weights -> bf16 ----
    f32_to_bf16_k<<<(HID * IN + 255) / 256, 256, 0, stream>>>(W0, Wb0, HID * IN);
    f32_to_bf16_k<<<(HID * HID + 255) / 256, 256, 0, stream>>>(W1, Wb1, HID * HID);
    f32_to_bf16_k<<<(OUT * HID + 255) / 256, 256, 0, stream>>>(W2, Wb2, OUT * HID);

    const int gblocks = (n + 127) / 128;
    const int sblocks = (n + 3) / 4;

    // ---- layer 0 ----
    gemm_bf16<512, 128, 128, 128, 64, false><<<gblocks, 256, 0, stream>>>(x, Wb0, g, n);
    spmm_csr_128<true><<<sblocks, 256, 0, stream>>>(row_ptr, col_s, val_s, g, h, n);

    // ---- layer 1 ----
    gemm_bf16<128, 128, 128, 128, 64, true><<<gblocks, 256, 0, stream>>>(h, Wb1, g, n);
    spmm_csr_128<true><<<sblocks, 256, 0, stream>>>(row_ptr, col_s, val_s, g, h, n);

    // ---- layer 2 ----
    gemm_bf16<128, 64, 128, 64, 64, true><<<gblocks, 256, 0, stream>>>(h, Wb2, g, n);
    spmm_csr_64f<<<sblocks, 256, 0, stream>>>(row_ptr, col_s, val_s, g, out, n);
}

// Round 4
// 766.404 us; speedup vs baseline: 1.7566x; 1.0895x over previous
//
#include <hip/hip_runtime.h>
#include <hip/hip_bf16.h>
#include <cstddef>

// GCN: h0 = relu(spmm(x@W0^T)); h1 = relu(spmm(h0@W1^T)); out = spmm(h1@W2^T)
// R4: GEMM gets m97-style 2-barrier software pipeline (prefetch next tile into
// registers during MFMA). SpMM: x4 edge unroll + packed (col,val) int2 edges.

typedef unsigned short ushort_t;
using frag_t = __attribute__((ext_vector_type(8))) short;   // 8 bf16
using accf4 = __attribute__((ext_vector_type(4))) float;    // 4 fp32

__device__ __forceinline__ ushort_t f2bf(float f) {
    unsigned int u = __float_as_uint(f);
    u += 0x7FFF + ((u >> 16) & 1);   // RNE
    return (ushort_t)(u >> 16);
}
__device__ __forceinline__ float bf2f(ushort_t u) {
    return __uint_as_float((unsigned int)u << 16);
}

// ---------------- CSR build ----------------

__global__ __launch_bounds__(256) void zero_i32(int* p, int n) {
    int i = blockIdx.x * 256 + threadIdx.x;
    if (i < n) p[i] = 0;
}

__global__ __launch_bounds__(256) void hist_kernel(const int* __restrict__ rows,
                                                   int* __restrict__ counts, int ne) {
    int e = blockIdx.x * 256 + threadIdx.x;
    if (e < ne) atomicAdd(&counts[rows[e]], 1);
}

__global__ __launch_bounds__(256) void block_totals(const int* __restrict__ counts,
                                                    int* __restrict__ bsums, int n) {
    __shared__ int s[256];
    int t = threadIdx.x;
    int i = blockIdx.x * 256 + t;
    s[t] = (i < n) ? counts[i] : 0;
    __syncthreads();
    for (int off = 128; off > 0; off >>= 1) {
        if (t < off) s[t] += s[t + off];
        __syncthreads();
    }
    if (t == 0) bsums[blockIdx.x] = s[0];
}

__global__ __launch_bounds__(512) void scan_sums(int* bsums, int nb) {
    __shared__ int s[512];
    int t = threadIdx.x;
    int v = (t < nb) ? bsums[t] : 0;
    s[t] = v;
    __syncthreads();
    for (int off = 1; off < 512; off *= 2) {
        int u = (t >= off) ? s[t - off] : 0;
        __syncthreads();
        s[t] += u;
        __syncthreads();
    }
    if (t < nb) bsums[t] = s[t] - v;  // exclusive
}

__global__ __launch_bounds__(256) void scan_final(const int* __restrict__ counts,
                                                  const int* __restrict__ bsums,
                                                  int* __restrict__ row_ptr,
                                                  int* __restrict__ cur, int n) {
    __shared__ int s[256];
    int t = threadIdx.x;
    int i = blockIdx.x * 256 + t;
    int v = (i < n) ? counts[i] : 0;
    s[t] = v;
    __syncthreads();
    for (int off = 1; off < 256; off *= 2) {
        int u = (t >= off) ? s[t - off] : 0;
        __syncthreads();
        s[t] += u;
        __syncthreads();
    }
    int excl = s[t] - v + bsums[blockIdx.x];
    if (i < n) {
        row_ptr[i] = excl;
        cur[i] = excl;
        if (i == n - 1) row_ptr[n] = excl + v;
    }
}

__global__ __launch_bounds__(256) void scatter_k(const int* __restrict__ rows,
                                                 const int* __restrict__ cols,
                                                 const float* __restrict__ vals,
                                                 int* __restrict__ cur,
                                                 int2* __restrict__ es, int ne) {
    int e = blockIdx.x * 256 + threadIdx.x;
    if (e >= ne) return;
    int r = rows[e];
    int p = atomicAdd(&cur[r], 1);
    es[p] = make_int2(cols[e], __float_as_int(vals[e]));
}

// ---------------- weight convert ----------------

__global__ __launch_bounds__(256) void f32_to_bf16_k(const float* __restrict__ a,
                                                     ushort_t* __restrict__ b, int n) {
    int i = blockIdx.x * 256 + threadIdx.x;
    if (i < n) b[i] = f2bf(a[i]);
}

// ---------------- bf16 MFMA GEMM: C[M,N] = A[M,K] * W[N,K]^T ----------------
// 2-barrier pipelined K-loop: prefetch tile t+1 into registers while MFMAing
// tile t from LDS. ABF16: A already bf16; else fp32 converted at LDS write.

template <int K, int N, int BM, int BN, int BK, bool ABF16>
__global__ __launch_bounds__(256) void gemm_bf16(const void* __restrict__ Av,
                                                 const ushort_t* __restrict__ Wb,
                                                 ushort_t* __restrict__ C, int M) {
    constexpr int WM = BM / 2, WN = BN / 2;
    constexpr int TI = WM / 16, TJ = WN / 16;
    constexpr int LDA = BK + 8;
    constexpr int T = K / BK;
    constexpr int A_PER_F = BM * BK / 4 / 256;
    constexpr int A_PER_B = BM * BK / 8 / 256;
    constexpr int B_PER = BN * BK / 8 / 256;

    __shared__ __align__(16) ushort_t As[BM][LDA];
    __shared__ __align__(16) ushort_t Bs[BN][LDA];

    const int tid = threadIdx.x;
    const int lane = tid & 63;
    const int wid = tid >> 6;
    const int wm = wid >> 1, wn = wid & 1;
    const int rowBase = blockIdx.x * BM;
    const int lrow = lane & 15, kq = lane >> 4;

    float4 aF[ABF16 ? 1 : A_PER_F];
    uint4 aB[ABF16 ? A_PER_B : 1];
    uint4 bR[B_PER];

    auto loadTile = [&](int k0) {
        if constexpr (ABF16) {
            const ushort_t* A = (const ushort_t*)Av;
#pragma unroll
            for (int i = 0; i < A_PER_B; i++) {
                int idx = tid + i * 256;
                int r = idx / (BK / 8), c8 = idx % (BK / 8);
                int grow = rowBase + r;
                aB[i] = (grow < M) ? *(const uint4*)(A + (size_t)grow * K + k0 + c8 * 8)
                                   : make_uint4(0, 0, 0, 0);
            }
        } else {
            const float* A = (const float*)Av;
#pragma unroll
            for (int i = 0; i < A_PER_F; i++) {
                int idx = tid + i * 256;
                int r = idx / (BK / 4), c4 = idx % (BK / 4);
                int grow = rowBase + r;
                aF[i] = (grow < M) ? *(const float4*)(A + (size_t)grow * K + k0 + c4 * 4)
                                   : make_float4(0.f, 0.f, 0.f, 0.f);
            }
        }
#pragma unroll
        for (int i = 0; i < B_PER; i++) {
            int idx = tid + i * 256;
            int r = idx / (BK / 8), c8 = idx % (BK / 8);
            bR[i] = *(const uint4*)(Wb + (size_t)r * K + k0 + c8 * 8);
        }
    };
    auto storeTile = [&]() {
        if constexpr (ABF16) {
#pragma unroll
            for (int i = 0; i < A_PER_B; i++) {
                int idx = tid + i * 256;
                int r = idx / (BK / 8), c8 = idx % (BK / 8);
                *(uint4*)&As[r][c8 * 8] = aB[i];
            }
        } else {
#pragma unroll
            for (int i = 0; i < A_PER_F; i++) {
                int idx = tid + i * 256;
                int r = idx / (BK / 4), c4 = idx % (BK / 4);
                ushort_t p[4] = {f2bf(aF[i].x), f2bf(aF[i].y), f2bf(aF[i].z), f2bf(aF[i].w)};
                *(uint2*)&As[r][c4 * 4] = *(uint2*)p;
            }
        }
#pragma unroll
        for (int i = 0; i < B_PER; i++) {
            int idx = tid + i * 256;
            int r = idx / (BK / 8), c8 = idx % (BK / 8);
            *(uint4*)&Bs[r][c8 * 8] = bR[i];
        }
    };

    accf4 acc[TI][TJ];
#pragma unroll
    for (int i = 0; i < TI; i++)
#pragma unroll
        for (int j = 0; j < TJ; j++) acc[i][j] = accf4{0.f, 0.f, 0.f, 0.f};

    loadTile(0);
    storeTile();
    __syncthreads();

    for (int t = 0; t < T; t++) {
        if (t + 1 < T) loadTile((t + 1) * BK);   // in flight during MFMA
#pragma unroll
        for (int ks = 0; ks < BK / 32; ks++) {
            const int kb = ks * 32 + kq * 8;
            frag_t a[TI], b[TJ];
#pragma unroll
            for (int i = 0; i < TI; i++)
                a[i] = *(const frag_t*)&As[wm * WM + i * 16 + lrow][kb];
#pragma unroll
            for (int j = 0; j < TJ; j++)
                b[j] = *(const frag_t*)&Bs[wn * WN + j * 16 + lrow][kb];
#pragma unroll
            for (int i = 0; i < TI; i++)
#pragma unroll
                for (int j = 0; j < TJ; j++)
                    acc[i][j] = __builtin_amdgcn_mfma_f32_16x16x32_bf16(
                        a[i], b[j], acc[i][j], 0, 0, 0);
        }
        __syncthreads();
        if (t + 1 < T) {
            storeTile();
            __syncthreads();
        }
    }

    // epilogue: C/D layout col=lane&15, row=(lane>>4)*4+reg; write bf16
#pragma unroll
    for (int i = 0; i < TI; i++) {
#pragma unroll
        for (int j = 0; j < TJ; j++) {
            int col = wn * WN + j * 16 + lrow;
#pragma unroll
            for (int r = 0; r < 4; r++) {
                int grow = rowBase + wm * WM + i * 16 + kq * 4 + r;
                if (grow < M) C[(size_t)grow * N + col] = f2bf(acc[i][j][r]);
            }
        }
    }
}

// ---------------- SpMM (CSR, wave per row, bf16 gather, x4 unroll) ----------

template <bool RELU>
__global__ __launch_bounds__(256) void spmm_csr_128(const int* __restrict__ row_ptr,
                                                    const int2* __restrict__ es,
                                                    const ushort_t* __restrict__ G,
                                                    ushort_t* __restrict__ H, int n) {
    int row = blockIdx.x * 4 + (threadIdx.x >> 6);
    int lane = threadIdx.x & 63;
    if (row >= n) return;
    int s = row_ptr[row];
    int e = row_ptr[row + 1];
    float a0 = 0.f, a1 = 0.f;
    int p = s;
    for (; p + 3 < e; p += 4) {
        int2 e0 = es[p], e1 = es[p + 1], e2 = es[p + 2], e3 = es[p + 3];
        unsigned u0 = *(const unsigned*)(G + (size_t)e0.x * 128 + lane * 2);
        unsigned u1 = *(const unsigned*)(G + (size_t)e1.x * 128 + lane * 2);
        unsigned u2 = *(const unsigned*)(G + (size_t)e2.x * 128 + lane * 2);
        unsigned u3 = *(const unsigned*)(G + (size_t)e3.x * 128 + lane * 2);
        float v0 = __int_as_float(e0.y), v1 = __int_as_float(e1.y);
        float v2 = __int_as_float(e2.y), v3 = __int_as_float(e3.y);
        a0 += v0 * bf2f((ushort_t)(u0 & 0xffff)); a1 += v0 * bf2f((ushort_t)(u0 >> 16));
        a0 += v1 * bf2f((ushort_t)(u1 & 0xffff)); a1 += v1 * bf2f((ushort_t)(u1 >> 16));
        a0 += v2 * bf2f((ushort_t)(u2 & 0xffff)); a1 += v2 * bf2f((ushort_t)(u2 >> 16));
        a0 += v3 * bf2f((ushort_t)(u3 & 0xffff)); a1 += v3 * bf2f((ushort_t)(u3 >> 16));
    }
    for (; p < e; p++) {
        int2 e0 = es[p];
        unsigned u0 = *(const unsigned*)(G + (size_t)e0.x * 128 + lane * 2);
        float v0 = __int_as_float(e0.y);
        a0 += v0 * bf2f((ushort_t)(u0 & 0xffff)); a1 += v0 * bf2f((ushort_t)(u0 >> 16));
    }
    if (RELU) { a0 = fmaxf(a0, 0.f); a1 = fmaxf(a1, 0.f); }
    unsigned packed = (unsigned)f2bf(a0) | ((unsigned)f2bf(a1) << 16);
    *(unsigned*)(H + (size_t)row * 128 + lane * 2) = packed;
}

__global__ __launch_bounds__(256) void spmm_csr_64f(const int* __restrict__ row_ptr,
                                                    const int2* __restrict__ es,
                                                    const ushort_t* __restrict__ G,
                                                    float* __restrict__ H, int n) {
    int row = blockIdx.x * 4 + (threadIdx.x >> 6);
    int lane = threadIdx.x & 63;
    if (row >= n) return;
    int s = row_ptr[row];
    int e = row_ptr[row + 1];
    float a0 = 0.f;
    int p = s;
    for (; p + 3 < e; p += 4) {
        int2 e0 = es[p], e1 = es[p + 1], e2 = es[p + 2], e3 = es[p + 3];
        float g0 = bf2f(G[(size_t)e0.x * 64 + lane]);
        float g1 = bf2f(G[(size_t)e1.x * 64 + lane]);
        float g2 = bf2f(G[(size_t)e2.x * 64 + lane]);
        float g3 = bf2f(G[(size_t)e3.x * 64 + lane]);
        a0 += __int_as_float(e0.y) * g0 + __int_as_float(e1.y) * g1 +
              __int_as_float(e2.y) * g2 + __int_as_float(e3.y) * g3;
    }
    for (; p < e; p++) {
        a0 += __int_as_float(es[p].y) * bf2f(G[(size_t)es[p].x * 64 + lane]);
    }
    H[(size_t)row * 64 + lane] = a0;
}

static inline size_t align_up(size_t x, size_t a) { return (x + a - 1) & ~(a - 1); }

extern "C" void kernel_launch(void* const* d_in, const int* in_sizes, int n_in,
                              void* d_out, int out_size, void* d_ws, size_t ws_size,
                              hipStream_t stream) {
    const float* x = (const float*)d_in[0];
    const int* rows = (const int*)d_in[1];
    const int* cols = (const int*)d_in[2];
    const float* vals = (const float*)d_in[3];
    const float* W0 = (const float*)d_in[4];
    const float* W1 = (const float*)d_in[5];
    const float* W2 = (const float*)d_in[6];
    float* out = (float*)d_out;

    const int IN = 512, HID = 128, OUT = 64;
    const int n = in_sizes[0] / IN;   // 100000
    const int ne = in_sizes[1];       // 1600000

    // workspace carve-up
    char* ws = (char*)d_ws;
    size_t off = 0;
    ushort_t* g = (ushort_t*)(ws + off); off = align_up(off + (size_t)n * HID * 2, 512);
    ushort_t* h = (ushort_t*)(ws + off); off = align_up(off + (size_t)n * HID * 2, 512);
    int2* es = (int2*)(ws + off); off = align_up(off + (size_t)ne * 8, 512);
    int* counts = (int*)(ws + off); off = align_up(off + (size_t)n * 4, 512);
    int* row_ptr = (int*)(ws + off); off = align_up(off + (size_t)(n + 1) * 4, 512);
    int* cur = (int*)(ws + off); off = align_up(off + (size_t)n * 4, 512);
    int* bsums = (int*)(ws + off); off = align_up(off + 512 * 4, 512);
    ushort_t* Wb0 = (ushort_t*)(ws + off); off = align_up(off + (size_t)HID * IN * 2, 512);
    ushort_t* Wb1 = (ushort_t*)(ws + off); off = align_up(off + (size_t)HID * HID * 2, 512);
    ushort_t* Wb2 = (ushort_t*)(ws + off); off = align_up(off + (size_t)OUT * HID * 2, 512);

    const int nb = (n + 255) / 256;
    const int eb = (ne + 255) / 256;

    // ---- build CSR ----
    zero_i32<<<nb, 256, 0, stream>>>(counts, n);
    hist_kernel<<<eb, 256, 0, stream>>>(rows, counts, ne);
    block_totals<<<nb, 256, 0, stream>>>(counts, bsums, n);
    scan_sums<<<1, 512, 0, stream>>>(bsums, nb);
    scan_final<<<nb, 256, 0, stream>>>(counts, bsums, row_ptr, cur, n);
    scatter_k<<<eb, 256, 0, stream>>>(rows, cols, vals, cur, es, ne);

    // ---- weights -> bf16 ----
    f32_to_bf16_k<<<(HID * IN + 255) / 256, 256, 0, stream>>>(W0, Wb0, HID * IN);
    f32_to_bf16_k<<<(HID * HID + 255) / 256, 256, 0, stream>>>(W1, Wb1, HID * HID);
    f32_to_bf16_k<<<(OUT * HID + 255) / 256, 256, 0, stream>>>(W2, Wb2, OUT * HID);

    const int gblocks = (n + 127) / 128;
    const int sblocks = (n + 3) / 4;

    // ---- layer 0 ----
    gemm_bf16<512, 128, 128, 128, 64, false><<<gblocks, 256, 0, stream>>>(x, Wb0, g, n);
    spmm_csr_128<true><<<sblocks, 256, 0, stream>>>(row_ptr, es, g, h, n);

    // ---- layer 1 ----
    gemm_bf16<128, 128, 128, 128, 64, true><<<gblocks, 256, 0, stream>>>(h, Wb1, g, n);
    spmm_csr_128<true><<<sblocks, 256, 0, stream>>>(row_ptr, es, g, h, n);

    // ---- layer 2 ----
    gemm_bf16<128, 64, 128, 64, 64, true><<<gblocks, 256, 0, stream>>>(h, Wb2, g, n);
    spmm_csr_64f<<<sblocks, 256, 0, stream>>>(row_ptr, es, g, out, n);
}